// Round 6
// baseline (433.285 us; speedup 1.0000x reference)
//
#include <hip/hip_runtime.h>
#include <stdint.h>
#include <stddef.h>

// Problem constants (MultiHeadAttention_52759378264454)
constexpr int T_SEQ = 1024;
constexpr int BATCH = 8;
constexpr int DIN   = 256;
constexpr int NH    = 8;
constexpr int EH    = 512;
constexpr int HE    = NH * EH;   // 4096
constexpr float SCALE = 0.044194173824159216f; // 1/sqrt(512)

typedef __attribute__((ext_vector_type(8)))  short s16x8;
typedef __attribute__((ext_vector_type(4)))  short s16x4;
typedef __attribute__((ext_vector_type(16))) float f32x16;

__device__ __forceinline__ short f2bf(float f) {
  union { float f; uint32_t u; } c; c.f = f;
  uint32_t u = c.u;
  u += 0x7fffu + ((u >> 16) & 1u);   // RNE
  return (short)(u >> 16);
}
__device__ __forceinline__ float bf2f(short s) {
  union { uint32_t u; float f; } c; c.u = ((uint32_t)(uint16_t)s) << 16;
  return c.f;
}

// async global->LDS, 16B/lane. LDS dest = wave-uniform base + lane*16 (HW).
__device__ __forceinline__ void gload16(const short* g, short* l) {
  __builtin_amdgcn_global_load_lds(
      (__attribute__((address_space(1))) void*)(void*)const_cast<short*>(g),
      (__attribute__((address_space(3))) void*)(void*)l, 16, 0, 0);
}

#define WAITVM(N) asm volatile("s_waitcnt vmcnt(" #N ")" ::: "memory")
#define BARF do { asm volatile("" ::: "memory"); __builtin_amdgcn_s_barrier(); \
                  asm volatile("" ::: "memory"); } while (0)

// per-element scale of a bf16x8 frag by 8 fp32 values (RNE back to bf16)
__device__ __forceinline__ s16x8 scale8(s16x8 a, float4 i0, float4 i1) {
  float iv[8] = { i0.x, i0.y, i0.z, i0.w, i1.x, i1.y, i1.z, i1.w };
  s16x8 o;
#pragma unroll
  for (int j = 0; j < 8; ++j) o[j] = f2bf(bf2f(a[j]) * iv[j]);
  return o;
}

// ---------------------------------------------------------------------------
// 8-wave 256x128 GEMM, BK=32, mfma_f32_32x32x16_bf16, double-buffered 48 KiB
// LDS, counted vmcnt (steady-state vmcnt(3), tile t+2 in flight).
// C[256,128] += A[256,K]*B[128,K]^T, K-major bf16. Waves 4wm x 2wn, 64x64 ea.
// SA: scale A-frags by invL[k_abs] (column softmax normalizer folded into P).
// ---------------------------------------------------------------------------
template<int NT, bool SA>   // K = NT*32
__device__ __forceinline__ void gemm32(const short* __restrict__ Ag, int lda,
                                       const short* __restrict__ Bg, int ldb,
                                       short* lds, const float* invL,
                                       f32x16 (&acc)[2][2])
{
  const int tid = threadIdx.x;
  const int l   = tid & 63, wv = tid >> 6;
  const int hi  = l >> 5;
  const int Rw  = (wv >> 1) * 64, Cw = (wv & 1) * 64;
  const int fl  = (l & 3) ^ ((l >> 2) & 3);

  int oA[2][2], oB[2][2];
#pragma unroll
  for (int kk = 0; kk < 2; ++kk) {
    int cp = (((kk << 1) | hi) ^ fl) * 8;
#pragma unroll
    for (int mi = 0; mi < 2; ++mi) oA[kk][mi] = (Rw + mi * 32 + (l & 31)) * 32 + cp;
#pragma unroll
    for (int ni = 0; ni < 2; ++ni) oB[kk][ni] = 8192 + (Cw + ni * 32 + (l & 31)) * 32 + cp;
  }

  const int rA0 = tid >> 2;
  const int sA0 = ((tid & 3) ^ ((rA0 & 3) ^ ((rA0 >> 2) & 3))) * 8;
  const int cA1 = tid + 512, rA1 = cA1 >> 2;
  const int sA1 = ((cA1 & 3) ^ ((rA1 & 3) ^ ((rA1 >> 2) & 3))) * 8;
  const int dA0 = (wv * 64) * 8, dA1 = (wv * 64 + 512) * 8, dB0 = 8192 + (wv * 64) * 8;

  auto stage = [&](int t) {
    short* slot = lds + (t & 1) * 12288;
    const int ko = t * 32;
    gload16(Ag + (size_t)rA0 * lda + ko + sA0, slot + dA0);
    gload16(Ag + (size_t)rA1 * lda + ko + sA1, slot + dA1);
    gload16(Bg + (size_t)rA0 * ldb + ko + sA0, slot + dB0);
  };

  stage(0); stage(1);

#pragma unroll 1
  for (int t = 0; t < NT; ++t) {
    const short* buf = lds + (t & 1) * 12288;
    if (t == NT - 1) { WAITVM(0); } else { WAITVM(3); }
    BARF;
#pragma unroll
    for (int kk = 0; kk < 2; ++kk) {
      s16x8 a0 = *(const s16x8*)(buf + oA[kk][0]);
      s16x8 a1 = *(const s16x8*)(buf + oA[kk][1]);
      s16x8 b0 = *(const s16x8*)(buf + oB[kk][0]);
      s16x8 b1 = *(const s16x8*)(buf + oB[kk][1]);
      if constexpr (SA) {
        const float* ip = invL + t * 32 + kk * 16 + hi * 8;
        float4 i0 = *(const float4*)ip;
        float4 i1 = *(const float4*)(ip + 4);
        a0 = scale8(a0, i0, i1);
        a1 = scale8(a1, i0, i1);
      }
      __builtin_amdgcn_s_setprio(1);
      acc[0][0] = __builtin_amdgcn_mfma_f32_32x32x16_bf16(a0, b0, acc[0][0], 0, 0, 0);
      acc[0][1] = __builtin_amdgcn_mfma_f32_32x32x16_bf16(a0, b1, acc[0][1], 0, 0, 0);
      acc[1][0] = __builtin_amdgcn_mfma_f32_32x32x16_bf16(a1, b0, acc[1][0], 0, 0, 0);
      acc[1][1] = __builtin_amdgcn_mfma_f32_32x32x16_bf16(a1, b1, acc[1][1], 0, 0, 0);
      __builtin_amdgcn_s_setprio(0);
    }
    BARF;
    if (t + 2 < NT) stage(t + 2);
  }
}

#define CROW(mi, reg) ((wv >> 1) * 64 + (mi) * 32 + ((reg) & 3) + 8 * ((reg) >> 2) + 4 * hi)
#define CCOL(ni)      ((wv & 1) * 64 + (ni) * 32 + (l & 31))

// ---------------------------------------------------------------------------
// K0: fused fp32->bf16 cast; Qb transposed to [b][t][d]; weights copied.
// ---------------------------------------------------------------------------
__global__ __launch_bounds__(256) void k_cvt_all(
    const float* __restrict__ Q,  const float* __restrict__ Wq,
    const float* __restrict__ Wk, const float* __restrict__ Wv,
    const float* __restrict__ Wo, short* __restrict__ dst)
{
  constexpr int N_Q = 524288;              // 1024*8*256/4
  constexpr int N_W = 262144;              // 8*512*256/4
  constexpr int TOT = N_Q + 4 * N_W;
  int i  = blockIdx.x * 256 + threadIdx.x;
  int st = gridDim.x * 256;
  for (; i < TOT; i += st) {
    const float* s; int off;
    if (i < N_Q) {
      int b = i >> 16, t = (i >> 6) & 1023, d4 = i & 63;
      s = Q; off = (t * 8 + b) * 64 + d4;
    }
    else if (i < N_Q + N_W)     { s = Wq; off = i - N_Q; }
    else if (i < N_Q + 2 * N_W) { s = Wk; off = i - N_Q - N_W; }
    else if (i < N_Q + 3 * N_W) { s = Wv; off = i - N_Q - 2 * N_W; }
    else                        { s = Wo; off = i - N_Q - 3 * N_W; }
    float4 v = ((const float4*)s)[off];
    s16x4 o = { f2bf(v.x), f2bf(v.y), f2bf(v.z), f2bf(v.w) };
    __builtin_nontemporal_store(o, (s16x4*)dst + i);
  }
}

// ---------------------------------------------------------------------------
// K1a: Q/K projection. C[m,e] = sum_d Qb[m,d]*W[h,e,d] + bias.
// grid (128, 2*HG). Sharer-aware XCD map: bx&7 == XCD (A-tile reuse in L2).
// ---------------------------------------------------------------------------
__global__ __launch_bounds__(512, 4) void k_projqk(
    const short* __restrict__ Qb,
    const short* __restrict__ Wqb, const short* __restrict__ Wkb,
    const float* __restrict__ bq, const float* __restrict__ bk,
    short* __restrict__ qb, short* __restrict__ kb, int h0, int HG)
{
  __shared__ short lds[24576];
  int f = blockIdx.x + (blockIdx.y << 7);
  int bx = (f & 7) + 8 * ((f >> 3) & 3);
  int rest = f >> 5;
  int by = rest & 3, z = rest >> 2;           // z in [0, 2HG)
  int p = z / HG, hh = z % HG, h = h0 + hh;

  const short* W    = (p == 0 ? Wqb : Wkb) + ((size_t)h * EH + (size_t)by * 128) * DIN;
  const float* bias = (p == 0 ? bq  : bk ) + h * EH + by * 128;
  short* outp       = (p == 0 ? qb  : kb ) + (size_t)hh * BATCH * T_SEQ * EH;
  const short* Ag   = Qb + (size_t)bx * 256 * DIN;

  f32x16 acc[2][2] = {};
  gemm32<DIN / 32, false>(Ag, DIN, W, DIN, lds, nullptr, acc);

  const int l = threadIdx.x & 63, wv = threadIdx.x >> 6, hi = l >> 5;
#pragma unroll
  for (int ni = 0; ni < 2; ++ni) {
    int coll = CCOL(ni);
    float bia = bias[coll];
    int e = by * 128 + coll;
#pragma unroll
    for (int mi = 0; mi < 2; ++mi)
#pragma unroll
      for (int reg = 0; reg < 16; ++reg) {
        int m = bx * 256 + CROW(mi, reg);
        __builtin_nontemporal_store(f2bf(acc[mi][ni][reg] + bia),
                                    &outp[(size_t)m * EH + e]);
      }
  }
}

// ---------------------------------------------------------------------------
// K1b: V projection TRANSPOSED: C[e, m] = sum_d Wv[h,e,d]*Qb[m,d] + bv[h,e]
// (operand swap: A = Wv K-major, B = Qb K-major) -> vT[hh][e][m], m=b*1024+t
// grid (128, HG)
// ---------------------------------------------------------------------------
__global__ __launch_bounds__(512, 4) void k_projv(
    const short* __restrict__ Qb, const short* __restrict__ Wvb,
    const float* __restrict__ bv, short* __restrict__ vT, int h0, int HG)
{
  __shared__ short lds[24576];
  int f = blockIdx.x + (blockIdx.y << 7);
  int bn = (f & 7) + 8 * ((f >> 3) & 7);      // [0,64) m-tile
  int rest = f >> 6;
  int bm = rest & 1, hh = rest >> 1, h = h0 + hh;

  const short* Ag = Wvb + ((size_t)h * EH + (size_t)bm * 256) * DIN;
  const short* Bg = Qb + (size_t)bn * 128 * DIN;

  f32x16 acc[2][2] = {};
  gemm32<DIN / 32, false>(Ag, DIN, Bg, DIN, lds, nullptr, acc);

  short* outp = vT + (size_t)hh * EH * (BATCH * T_SEQ);
  const int l = threadIdx.x & 63, wv = threadIdx.x >> 6, hi = l >> 5;
#pragma unroll
  for (int ni = 0; ni < 2; ++ni) {
    int m = bn * 128 + CCOL(ni);
#pragma unroll
    for (int mi = 0; mi < 2; ++mi)
#pragma unroll
      for (int reg = 0; reg < 16; ++reg) {
        int e = bm * 256 + CROW(mi, reg);
        float bia = bv[h * EH + e];
        __builtin_nontemporal_store(f2bf(acc[mi][ni][reg] + bia),
                                    &outp[(size_t)e * (BATCH * T_SEQ) + m]);
      }
  }
}

// ---------------------------------------------------------------------------
// K3a: P[t,s] = exp(SCALE*q.k) bf16 (unnormalized) + per-block column sums.
// grid (4, 8, HG*8); same-z blocks grouped per XCD (q/k L2 reuse).
// ---------------------------------------------------------------------------
__global__ __launch_bounds__(512, 4) void k_pgen(
    const short* __restrict__ qb, const short* __restrict__ kb,
    short* __restrict__ Pbuf, float* __restrict__ colpart, int HG)
{
  __shared__ short lds[24576];
  int f = blockIdx.x + (blockIdx.y << 2) + (blockIdx.z << 5);
  int xcd = f & 7, rest = f >> 3;
  int zi = rest % HG, rb = rest / HG;
  int z = xcd * HG + zi;
  int bx = rb & 3, by = rb >> 2;

  const short* Ag = qb + (size_t)z * T_SEQ * EH + (size_t)bx * 256 * EH;
  const short* Bg = kb + (size_t)z * T_SEQ * EH + (size_t)by * 128 * EH;

  f32x16 acc[2][2] = {};
  gemm32<EH / 32, false>(Ag, EH, Bg, EH, lds, nullptr, acc);

  short* Pb = Pbuf + (size_t)z * T_SEQ * T_SEQ;
  const int l = threadIdx.x & 63, wv = threadIdx.x >> 6, hi = l >> 5;

  float cs[2] = {0.f, 0.f};
#pragma unroll
  for (int ni = 0; ni < 2; ++ni) {
    int s = by * 128 + CCOL(ni);
#pragma unroll
    for (int mi = 0; mi < 2; ++mi)
#pragma unroll
      for (int reg = 0; reg < 16; ++reg) {
        int tq = bx * 256 + CROW(mi, reg);
        float ev = __expf(acc[mi][ni][reg] * SCALE);
        cs[ni] += ev;
        __builtin_nontemporal_store(f2bf(ev), &Pb[(size_t)tq * T_SEQ + s]);
      }
  }
  cs[0] += __shfl_xor(cs[0], 32);
  cs[1] += __shfl_xor(cs[1], 32);
  float* csL = (float*)lds;
  if (l < 32) {
#pragma unroll
    for (int ni = 0; ni < 2; ++ni) csL[(wv >> 1) * 128 + CCOL(ni)] = cs[ni];
  }
  __syncthreads();
  if (threadIdx.x < 128) {
    float tot = csL[threadIdx.x] + csL[128 + threadIdx.x] +
                csL[256 + threadIdx.x] + csL[384 + threadIdx.x];
    colpart[((size_t)z * 4 + bx) * T_SEQ + by * 128 + threadIdx.x] = tot;
  }
}

// K2: invs[z*T + s] = 1 / sum_tt colpart[(z*4+tt)*T + s]
__global__ __launch_bounds__(256) void k_invsum(const float* __restrict__ colpart,
                                                float* __restrict__ invs, int HB)
{
  int i = blockIdx.x * 256 + threadIdx.x;
  if (i < HB * T_SEQ) {
    int hb = i >> 10, s = i & (T_SEQ - 1);
    float sum = 0.f;
#pragma unroll
    for (int tt = 0; tt < 4; ++tt) sum += colpart[((size_t)hb * 4 + tt) * T_SEQ + s];
    invs[i] = 1.0f / sum;
  }
}

// ---------------------------------------------------------------------------
// K3b: O[t,e] = sum_s (P[t,s]*inv[s]) * vT[e,s] -> Hmat[(b*T+t), h*EH+e]
// grid (4, 4, HG*8); same-z grouped per XCD. inv staged in LDS (+4KB).
// ---------------------------------------------------------------------------
__global__ __launch_bounds__(512, 3) void k_ogemm(
    const short* __restrict__ Pbuf, const short* __restrict__ vT,
    const float* __restrict__ invs, short* __restrict__ Hmat, int h0, int HG)
{
  __shared__ short lds[26624];     // 48KB gemm + 4KB invL
  int f = blockIdx.x + (blockIdx.y << 2) + (blockIdx.z << 4);
  int xcd = f & 7, rest = f >> 3;
  int zi = rest % HG, rb = rest / HG;
  int z = xcd * HG + zi;
  int bx = rb & 3, by = rb >> 2;
  const int hh = z >> 3, b = z & 7, h = h0 + hh;

  float* invL = (float*)(lds + 24576);
  const float* ig = invs + (size_t)z * T_SEQ;
  invL[threadIdx.x]       = ig[threadIdx.x];
  invL[threadIdx.x + 512] = ig[threadIdx.x + 512];
  __syncthreads();

  const short* Ag = Pbuf + (size_t)z * T_SEQ * T_SEQ + (size_t)bx * 256 * T_SEQ;
  const short* Bg = vT + ((size_t)hh * EH + (size_t)by * 128) * (BATCH * T_SEQ)
                       + (size_t)b * T_SEQ;

  f32x16 acc[2][2] = {};
  gemm32<T_SEQ / 32, true>(Ag, T_SEQ, Bg, BATCH * T_SEQ, lds, invL, acc);

  const int l = threadIdx.x & 63, wv = threadIdx.x >> 6, hi = l >> 5;
#pragma unroll
  for (int ni = 0; ni < 2; ++ni) {
    int e = by * 128 + CCOL(ni);
#pragma unroll
    for (int mi = 0; mi < 2; ++mi)
#pragma unroll
      for (int reg = 0; reg < 16; ++reg) {
        int tq = bx * 256 + CROW(mi, reg);
        __builtin_nontemporal_store(f2bf(acc[mi][ni][reg]),
            &Hmat[((size_t)b * T_SEQ + tq) * HE + (size_t)h * EH + e]);
      }
  }
}

// ---------------------------------------------------------------------------
// K4a: split-K(4) output GEMM. part[ks][m][d] over K=1024 slice. grid (32,2,4)
// ---------------------------------------------------------------------------
__global__ __launch_bounds__(512, 4) void k_final(
    const short* __restrict__ Hmat, const short* __restrict__ Wob,
    float* __restrict__ part)
{
  __shared__ short lds[24576];
  int orig = blockIdx.x + (blockIdx.y << 5) + (blockIdx.z << 6);
  int swz  = (orig & 7) * 32 + (orig >> 3);     // nwg = 256
  const int bx = swz & 31, by = (swz >> 5) & 1, ks = swz >> 6;

  const short* Ag = Hmat + (size_t)bx * 256 * HE + (size_t)ks * 1024;
  const short* Bg = Wob  + (size_t)by * 128 * HE + (size_t)ks * 1024;

  f32x16 acc[2][2] = {};
  gemm32<1024 / 32, false>(Ag, HE, Bg, HE, lds, nullptr, acc);

  float* pp = part + (size_t)ks * (T_SEQ * BATCH) * DIN;
  const int l = threadIdx.x & 63, wv = threadIdx.x >> 6, hi = l >> 5;
#pragma unroll
  for (int ni = 0; ni < 2; ++ni) {
    int d = by * 128 + CCOL(ni);
#pragma unroll
    for (int mi = 0; mi < 2; ++mi)
#pragma unroll
      for (int reg = 0; reg < 16; ++reg) {
        int m = bx * 256 + CROW(mi, reg);
        __builtin_nontemporal_store(acc[mi][ni][reg], &pp[(size_t)m * DIN + d]);
      }
  }
}

// K4b: out[(t*B+b), d] = sum_ks part[ks][(b*T+t)][d] + bo[d]
__global__ __launch_bounds__(256) void k_red(const float* __restrict__ part,
                                             const float* __restrict__ bo,
                                             float* __restrict__ out)
{
  int i = blockIdx.x * 256 + threadIdx.x;   // over 8192*64 float4s
  int m = i >> 6, d4 = i & 63;
  float4 s = ((const float4*)part)[i];
#pragma unroll
  for (int ks = 1; ks < 4; ++ks) {
    float4 p = ((const float4*)(part + (size_t)ks * T_SEQ * BATCH * DIN))[i];
    s.x += p.x; s.y += p.y; s.z += p.z; s.w += p.w;
  }
  float4 b4 = ((const float4*)bo)[d4];
  s.x += b4.x; s.y += b4.y; s.z += b4.z; s.w += b4.w;
  int t = m & 1023, b = m >> 10;
  ((float4*)out)[(t * 8 + b) * 64 + d4] = s;
}

// ---------------------------------------------------------------------------
extern "C" void kernel_launch(void* const* d_in, const int* in_sizes, int n_in,
                              void* d_out, int out_size, void* d_ws, size_t ws_size,
                              hipStream_t stream)
{
  const float* Q  = (const float*)d_in[0];
  const float* Wq = (const float*)d_in[1];
  const float* bq = (const float*)d_in[2];
  const float* Wk = (const float*)d_in[3];
  const float* bk = (const float*)d_in[4];
  const float* Wv = (const float*)d_in[5];
  const float* bv = (const float*)d_in[6];
  const float* Wo = (const float*)d_in[7];
  const float* bo = (const float*)d_in[8];
  float* out = (float*)d_out;

  // ---- sizes ----
  const size_t QB_B   = (size_t)T_SEQ * BATCH * DIN * 2;       //  4 MiB
  const size_t W_B    = (size_t)NH * EH * DIN * 2;             //  2 MiB each
  const size_t WO_B   = (size_t)DIN * HE * 2;                  //  2 MiB
  const size_t HMAT_B = (size_t)T_SEQ * BATCH * HE * 2;        // 64 MiB
  const size_t PART_B = (size_t)4 * T_SEQ * BATCH * DIN * 4;   // 32 MiB
  const size_t QKV1   = (size_t)BATCH * T_SEQ * EH * 2;        //  8 MiB / head
  const size_t P1     = (size_t)BATCH * T_SEQ * T_SEQ * 2;     // 16 MiB / head
  const size_t CP1    = (size_t)BATCH * 4 * T_SEQ * 4;         // 128 KiB / head
  const size_t INV1   = (size_t)BATCH * T_SEQ * 4;             //  32 KiB / head
  const size_t inputsB = QB_B + 3 * W_B + WO_B;                // 12 MiB contiguous

  // ---- largest HG whose plan fits (aliases: part <-> P) ----
  int HG = 8;
  for (; HG > 1; HG >>= 1) {
    size_t share = ((size_t)HG * P1 > PART_B) ? (size_t)HG * P1 : PART_B;
    size_t tot = inputsB + 3 * (size_t)HG * QKV1 + share + HMAT_B
               + (size_t)HG * (CP1 + INV1) + 8192;
    if (tot <= ws_size) break;
  }
  size_t shareB = ((size_t)HG * P1 > PART_B) ? (size_t)HG * P1 : PART_B;

  char* w = (char*)d_ws;
  auto alloc = [&](size_t bytes) {
    char* p = w;
    w += (bytes + 255) & ~(size_t)255;
    return p;
  };
  short* Qb   = (short*)alloc(QB_B);
  short* Wqb  = (short*)alloc(W_B);
  short* Wkb  = (short*)alloc(W_B);
  short* Wvb  = (short*)alloc(W_B);
  short* Wob  = (short*)alloc(WO_B);
  float* cpart= (float*)alloc((size_t)HG * CP1);
  float* invs = (float*)alloc((size_t)HG * INV1);
  short* qb   = (short*)alloc((size_t)HG * QKV1);
  short* kb   = (short*)alloc((size_t)HG * QKV1);
  short* vT   = (short*)alloc((size_t)HG * QKV1);
  char*  shr  = alloc(shareB);                      // P during loop; part after
  short* Hmat = (short*)alloc(HMAT_B);

  short* Pbuf = (short*)shr;
  float* part = (float*)shr;

  k_cvt_all<<<dim3(2048), 256, 0, stream>>>(Q, Wq, Wk, Wv, Wo, Qb);

  for (int h0 = 0; h0 < NH; h0 += HG) {
    k_projqk<<<dim3(128, 2 * HG), 512, 0, stream>>>(Qb, Wqb, Wkb, bq, bk,
                                                    qb, kb, h0, HG);
    k_projv <<<dim3(128, HG), 512, 0, stream>>>(Qb, Wvb, bv, vT, h0, HG);
    k_pgen  <<<dim3(4, 8, HG * 8), 512, 0, stream>>>(qb, kb, Pbuf, cpart, HG);
    k_invsum<<<dim3(HG * 32), 256, 0, stream>>>(cpart, invs, HG * 8);
    k_ogemm <<<dim3(4, 4, HG * 8), 512, 0, stream>>>(Pbuf, vT, invs, Hmat, h0, HG);
  }
  k_final<<<dim3(32, 2, 4), 512, 0, stream>>>(Hmat, Wob, part);
  k_red  <<<dim3(T_SEQ * BATCH * DIN / 4 / 256), 256, 0, stream>>>(part, bo, out);
}

// Round 7
// 372.095 us; speedup vs baseline: 1.1644x; 1.1644x over previous
//
#include <hip/hip_runtime.h>
#include <stdint.h>
#include <stddef.h>

// Problem constants (MultiHeadAttention_52759378264454)
constexpr int T_SEQ = 1024;
constexpr int BATCH = 8;
constexpr int DIN   = 256;
constexpr int NH    = 8;
constexpr int EH    = 512;
constexpr int HE    = NH * EH;   // 4096
constexpr float SCALE = 0.044194173824159216f; // 1/sqrt(512)

typedef __attribute__((ext_vector_type(8)))  short s16x8;
typedef __attribute__((ext_vector_type(4)))  short s16x4;
typedef __attribute__((ext_vector_type(16))) float f32x16;

__device__ __forceinline__ short f2bf(float f) {
  union { float f; uint32_t u; } c; c.f = f;
  uint32_t u = c.u;
  u += 0x7fffu + ((u >> 16) & 1u);   // RNE
  return (short)(u >> 16);
}
__device__ __forceinline__ float bf2f(short s) {
  union { uint32_t u; float f; } c; c.u = ((uint32_t)(uint16_t)s) << 16;
  return c.f;
}

// async global->LDS, 16B/lane. LDS dest = wave-uniform base + lane*16 (HW).
__device__ __forceinline__ void gload16(const short* g, short* l) {
  __builtin_amdgcn_global_load_lds(
      (__attribute__((address_space(1))) void*)(void*)const_cast<short*>(g),
      (__attribute__((address_space(3))) void*)(void*)l, 16, 0, 0);
}

#define WAITVM(N) asm volatile("s_waitcnt vmcnt(" #N ")" ::: "memory")
#define BARF do { asm volatile("" ::: "memory"); __builtin_amdgcn_s_barrier(); \
                  asm volatile("" ::: "memory"); } while (0)

// ---------------------------------------------------------------------------
// 8-wave 256x128 GEMM, BK=32, mfma_f32_32x32x16_bf16, double-buffered 48 KiB
// LDS, counted vmcnt (steady-state vmcnt(3), tile t+2 in flight).
// C[256,128] += A[256,K]*B[128,K]^T, K-major bf16. Waves 4wm x 2wn, 64x64 ea.
// ---------------------------------------------------------------------------
template<int NT>   // K = NT*32
__device__ __forceinline__ void gemm32(const short* __restrict__ Ag, int lda,
                                       const short* __restrict__ Bg, int ldb,
                                       short* lds, f32x16 (&acc)[2][2])
{
  const int tid = threadIdx.x;
  const int l   = tid & 63, wv = tid >> 6;
  const int hi  = l >> 5;
  const int Rw  = (wv >> 1) * 64, Cw = (wv & 1) * 64;
  const int fl  = (l & 3) ^ ((l >> 2) & 3);

  int oA[2][2], oB[2][2];
#pragma unroll
  for (int kk = 0; kk < 2; ++kk) {
    int cp = (((kk << 1) | hi) ^ fl) * 8;
#pragma unroll
    for (int mi = 0; mi < 2; ++mi) oA[kk][mi] = (Rw + mi * 32 + (l & 31)) * 32 + cp;
#pragma unroll
    for (int ni = 0; ni < 2; ++ni) oB[kk][ni] = 8192 + (Cw + ni * 32 + (l & 31)) * 32 + cp;
  }

  const int rA0 = tid >> 2;
  const int sA0 = ((tid & 3) ^ ((rA0 & 3) ^ ((rA0 >> 2) & 3))) * 8;
  const int cA1 = tid + 512, rA1 = cA1 >> 2;
  const int sA1 = ((cA1 & 3) ^ ((rA1 & 3) ^ ((rA1 >> 2) & 3))) * 8;
  const int dA0 = (wv * 64) * 8, dA1 = (wv * 64 + 512) * 8, dB0 = 8192 + (wv * 64) * 8;

  auto stage = [&](int t) {
    short* slot = lds + (t & 1) * 12288;
    const int ko = t * 32;
    gload16(Ag + (size_t)rA0 * lda + ko + sA0, slot + dA0);
    gload16(Ag + (size_t)rA1 * lda + ko + sA1, slot + dA1);
    gload16(Bg + (size_t)rA0 * ldb + ko + sA0, slot + dB0);
  };

  stage(0); stage(1);

#pragma unroll 1
  for (int t = 0; t < NT; ++t) {
    const short* buf = lds + (t & 1) * 12288;
    if (t == NT - 1) { WAITVM(0); } else { WAITVM(3); }
    BARF;
#pragma unroll
    for (int kk = 0; kk < 2; ++kk) {
      s16x8 a0 = *(const s16x8*)(buf + oA[kk][0]);
      s16x8 a1 = *(const s16x8*)(buf + oA[kk][1]);
      s16x8 b0 = *(const s16x8*)(buf + oB[kk][0]);
      s16x8 b1 = *(const s16x8*)(buf + oB[kk][1]);
      __builtin_amdgcn_s_setprio(1);
      acc[0][0] = __builtin_amdgcn_mfma_f32_32x32x16_bf16(a0, b0, acc[0][0], 0, 0, 0);
      acc[0][1] = __builtin_amdgcn_mfma_f32_32x32x16_bf16(a0, b1, acc[0][1], 0, 0, 0);
      acc[1][0] = __builtin_amdgcn_mfma_f32_32x32x16_bf16(a1, b0, acc[1][0], 0, 0, 0);
      acc[1][1] = __builtin_amdgcn_mfma_f32_32x32x16_bf16(a1, b1, acc[1][1], 0, 0, 0);
      __builtin_amdgcn_s_setprio(0);
    }
    BARF;
    if (t + 2 < NT) stage(t + 2);
  }
}

#define CROW(mi, reg) ((wv >> 1) * 64 + (mi) * 32 + ((reg) & 3) + 8 * ((reg) >> 2) + 4 * hi)
#define CCOL(ni)      ((wv & 1) * 64 + (ni) * 32 + (l & 31))

// ---------------------------------------------------------------------------
// K0: fused fp32->bf16 cast; Qb transposed to [b][t][d]; weights copied.
// ---------------------------------------------------------------------------
__global__ __launch_bounds__(256) void k_cvt_all(
    const float* __restrict__ Q,  const float* __restrict__ Wq,
    const float* __restrict__ Wk, const float* __restrict__ Wv,
    const float* __restrict__ Wo, short* __restrict__ dst)
{
  constexpr int N_Q = 524288;              // 1024*8*256/4
  constexpr int N_W = 262144;              // 8*512*256/4
  constexpr int TOT = N_Q + 4 * N_W;
  int i  = blockIdx.x * 256 + threadIdx.x;
  int st = gridDim.x * 256;
  for (; i < TOT; i += st) {
    const float* s; int off;
    if (i < N_Q) {
      int b = i >> 16, t = (i >> 6) & 1023, d4 = i & 63;
      s = Q; off = (t * 8 + b) * 64 + d4;
    }
    else if (i < N_Q + N_W)     { s = Wq; off = i - N_Q; }
    else if (i < N_Q + 2 * N_W) { s = Wk; off = i - N_Q - N_W; }
    else if (i < N_Q + 3 * N_W) { s = Wv; off = i - N_Q - 2 * N_W; }
    else                        { s = Wo; off = i - N_Q - 3 * N_W; }
    float4 v = ((const float4*)s)[off];
    s16x4 o = { f2bf(v.x), f2bf(v.y), f2bf(v.z), f2bf(v.w) };
    ((s16x4*)dst)[i] = o;
  }
}

// ---------------------------------------------------------------------------
// K1a: Q/K projection. C[m,e] = sum_d Qb[m,d]*W[h,e,d] + bias.
// grid (128, 2*HG). Sharer-aware XCD map: bx&7 == XCD (A-tile reuse in L2).
// ---------------------------------------------------------------------------
__global__ __launch_bounds__(512, 4) void k_projqk(
    const short* __restrict__ Qb,
    const short* __restrict__ Wqb, const short* __restrict__ Wkb,
    const float* __restrict__ bq, const float* __restrict__ bk,
    short* __restrict__ qb, short* __restrict__ kb, int h0, int HG)
{
  __shared__ short lds[24576];
  int f = blockIdx.x + (blockIdx.y << 7);
  int bx = (f & 7) + 8 * ((f >> 3) & 3);
  int rest = f >> 5;
  int by = rest & 3, z = rest >> 2;           // z in [0, 2HG)
  int p = z / HG, hh = z % HG, h = h0 + hh;

  const short* W    = (p == 0 ? Wqb : Wkb) + ((size_t)h * EH + (size_t)by * 128) * DIN;
  const float* bias = (p == 0 ? bq  : bk ) + h * EH + by * 128;
  short* outp       = (p == 0 ? qb  : kb ) + (size_t)hh * BATCH * T_SEQ * EH;
  const short* Ag   = Qb + (size_t)bx * 256 * DIN;

  f32x16 acc[2][2] = {};
  gemm32<DIN / 32>(Ag, DIN, W, DIN, lds, acc);

  const int l = threadIdx.x & 63, wv = threadIdx.x >> 6, hi = l >> 5;
#pragma unroll
  for (int ni = 0; ni < 2; ++ni) {
    int coll = CCOL(ni);
    float bia = bias[coll];
    int e = by * 128 + coll;
#pragma unroll
    for (int mi = 0; mi < 2; ++mi)
#pragma unroll
      for (int reg = 0; reg < 16; ++reg) {
        int m = bx * 256 + CROW(mi, reg);
        outp[(size_t)m * EH + e] = f2bf(acc[mi][ni][reg] + bia);
      }
  }
}

// ---------------------------------------------------------------------------
// K1b: V projection TRANSPOSED: C[e, m] = sum_d Wv[h,e,d]*Qb[m,d] + bv[h,e]
// -> vT[hh][e][m], m = b*1024 + t.  grid (128, HG)
// ---------------------------------------------------------------------------
__global__ __launch_bounds__(512, 4) void k_projv(
    const short* __restrict__ Qb, const short* __restrict__ Wvb,
    const float* __restrict__ bv, short* __restrict__ vT, int h0, int HG)
{
  __shared__ short lds[24576];
  int f = blockIdx.x + (blockIdx.y << 7);
  int bn = (f & 7) + 8 * ((f >> 3) & 7);      // [0,64) m-tile
  int rest = f >> 6;
  int bm = rest & 1, hh = rest >> 1, h = h0 + hh;

  const short* Ag = Wvb + ((size_t)h * EH + (size_t)bm * 256) * DIN;
  const short* Bg = Qb + (size_t)bn * 128 * DIN;

  f32x16 acc[2][2] = {};
  gemm32<DIN / 32>(Ag, DIN, Bg, DIN, lds, acc);

  short* outp = vT + (size_t)hh * EH * (BATCH * T_SEQ);
  const int l = threadIdx.x & 63, wv = threadIdx.x >> 6, hi = l >> 5;
#pragma unroll
  for (int ni = 0; ni < 2; ++ni) {
    int m = bn * 128 + CCOL(ni);
#pragma unroll
    for (int mi = 0; mi < 2; ++mi)
#pragma unroll
      for (int reg = 0; reg < 16; ++reg) {
        int e = bm * 256 + CROW(mi, reg);
        float bia = bv[h * EH + e];
        outp[(size_t)e * (BATCH * T_SEQ) + m] = f2bf(acc[mi][ni][reg] + bia);
      }
  }
}

// ---------------------------------------------------------------------------
// K3a: P[t,s] = exp(SCALE*q.k) bf16 (unnormalized) + per-block column sums.
// grid (4, 8, HG*8); same-z blocks grouped per XCD (q/k L2 reuse).
// ---------------------------------------------------------------------------
__global__ __launch_bounds__(512, 4) void k_pgen(
    const short* __restrict__ qb, const short* __restrict__ kb,
    short* __restrict__ Pbuf, float* __restrict__ colpart, int HG)
{
  __shared__ short lds[24576];
  int f = blockIdx.x + (blockIdx.y << 2) + (blockIdx.z << 5);
  int xcd = f & 7, rest = f >> 3;
  int zi = rest % HG, rb = rest / HG;
  int z = xcd * HG + zi;
  int bx = rb & 3, by = rb >> 2;

  const short* Ag = qb + (size_t)z * T_SEQ * EH + (size_t)bx * 256 * EH;
  const short* Bg = kb + (size_t)z * T_SEQ * EH + (size_t)by * 128 * EH;

  f32x16 acc[2][2] = {};
  gemm32<EH / 32>(Ag, EH, Bg, EH, lds, acc);

  short* Pb = Pbuf + (size_t)z * T_SEQ * T_SEQ;
  const int l = threadIdx.x & 63, wv = threadIdx.x >> 6, hi = l >> 5;

  float cs[2] = {0.f, 0.f};
#pragma unroll
  for (int ni = 0; ni < 2; ++ni) {
    int s = by * 128 + CCOL(ni);
#pragma unroll
    for (int mi = 0; mi < 2; ++mi)
#pragma unroll
      for (int reg = 0; reg < 16; ++reg) {
        int tq = bx * 256 + CROW(mi, reg);
        float ev = __expf(acc[mi][ni][reg] * SCALE);
        cs[ni] += ev;
        Pb[(size_t)tq * T_SEQ + s] = f2bf(ev);
      }
  }
  cs[0] += __shfl_xor(cs[0], 32);
  cs[1] += __shfl_xor(cs[1], 32);
  float* csL = (float*)lds;
  if (l < 32) {
#pragma unroll
    for (int ni = 0; ni < 2; ++ni) csL[(wv >> 1) * 128 + CCOL(ni)] = cs[ni];
  }
  __syncthreads();
  if (threadIdx.x < 128) {
    float tot = csL[threadIdx.x] + csL[128 + threadIdx.x] +
                csL[256 + threadIdx.x] + csL[384 + threadIdx.x];
    colpart[((size_t)z * 4 + bx) * T_SEQ + by * 128 + threadIdx.x] = tot;
  }
}

// ---------------------------------------------------------------------------
// K2: scale V in place by the softmax normalizer (fused invsum):
// vT[hh][e][m] *= 1 / sum_p colpart[(z*4+p)][t],  z = hh*8+b, m = b*1024+t
// grid (8 e-tiles, HG*8 z), 256 thr. Each block: 64 e-rows x 1024 t.
// ---------------------------------------------------------------------------
__global__ __launch_bounds__(256) void k_scalev(
    short* __restrict__ vT, const float* __restrict__ colpart, int HG)
{
  __shared__ float invL[1024];
  const int et = blockIdx.x, z = blockIdx.y;
  const int hh = z >> 3, b = z & 7;
  const int tid = threadIdx.x;

#pragma unroll
  for (int it = 0; it < 4; ++it) {
    int t = it * 256 + tid;
    float s = 0.f;
#pragma unroll
    for (int p = 0; p < 4; ++p) s += colpart[((size_t)z * 4 + p) * T_SEQ + t];
    invL[t] = 1.0f / s;
  }
  __syncthreads();

  short* base = vT + (size_t)hh * EH * (BATCH * T_SEQ)
                   + (size_t)et * 64 * (BATCH * T_SEQ) + (size_t)b * T_SEQ;
  for (int c = tid; c < 64 * 128; c += 256) {
    int row = c >> 7, col = (c & 127) * 8;
    short* p = &base[(size_t)row * (BATCH * T_SEQ) + col];
    s16x8 v = *(s16x8*)p;
#pragma unroll
    for (int j = 0; j < 8; ++j) v[j] = f2bf(bf2f(v[j]) * invL[col + j]);
    *(s16x8*)p = v;
  }
}

// ---------------------------------------------------------------------------
// K3b: O[t,e] = sum_s P[t,s]*vT[e,s] -> Hmat[(b*T+t), h*EH+e]
// grid (4, 4, HG*8); same-z grouped per XCD.
// ---------------------------------------------------------------------------
__global__ __launch_bounds__(512, 4) void k_ogemm(
    const short* __restrict__ Pbuf, const short* __restrict__ vT,
    short* __restrict__ Hmat, int h0, int HG)
{
  __shared__ short lds[24576];
  int f = blockIdx.x + (blockIdx.y << 2) + (blockIdx.z << 4);
  int xcd = f & 7, rest = f >> 3;
  int zi = rest % HG, rb = rest / HG;
  int z = xcd * HG + zi;
  int bx = rb & 3, by = rb >> 2;
  const int hh = z >> 3, b = z & 7, h = h0 + hh;

  const short* Ag = Pbuf + (size_t)z * T_SEQ * T_SEQ + (size_t)bx * 256 * T_SEQ;
  const short* Bg = vT + ((size_t)hh * EH + (size_t)by * 128) * (BATCH * T_SEQ)
                       + (size_t)b * T_SEQ;

  f32x16 acc[2][2] = {};
  gemm32<T_SEQ / 32>(Ag, T_SEQ, Bg, BATCH * T_SEQ, lds, acc);

  const int l = threadIdx.x & 63, wv = threadIdx.x >> 6, hi = l >> 5;
#pragma unroll
  for (int ni = 0; ni < 2; ++ni) {
    int e = by * 128 + CCOL(ni);
#pragma unroll
    for (int mi = 0; mi < 2; ++mi)
#pragma unroll
      for (int reg = 0; reg < 16; ++reg) {
        int tq = bx * 256 + CROW(mi, reg);
        Hmat[((size_t)b * T_SEQ + tq) * HE + (size_t)h * EH + e] = f2bf(acc[mi][ni][reg]);
      }
  }
}

// ---------------------------------------------------------------------------
// K4a: split-K(4) output GEMM. part[ks][m][d] over K=1024 slice. grid (32,2,4)
// ---------------------------------------------------------------------------
__global__ __launch_bounds__(512, 4) void k_final(
    const short* __restrict__ Hmat, const short* __restrict__ Wob,
    float* __restrict__ part)
{
  __shared__ short lds[24576];
  int orig = blockIdx.x + (blockIdx.y << 5) + (blockIdx.z << 6);
  int swz  = (orig & 7) * 32 + (orig >> 3);     // nwg = 256
  const int bx = swz & 31, by = (swz >> 5) & 1, ks = swz >> 6;

  const short* Ag = Hmat + (size_t)bx * 256 * HE + (size_t)ks * 1024;
  const short* Bg = Wob  + (size_t)by * 128 * HE + (size_t)ks * 1024;

  f32x16 acc[2][2] = {};
  gemm32<1024 / 32>(Ag, HE, Bg, HE, lds, acc);

  float* pp = part + (size_t)ks * (T_SEQ * BATCH) * DIN;
  const int l = threadIdx.x & 63, wv = threadIdx.x >> 6, hi = l >> 5;
#pragma unroll
  for (int ni = 0; ni < 2; ++ni) {
    int d = by * 128 + CCOL(ni);
#pragma unroll
    for (int mi = 0; mi < 2; ++mi)
#pragma unroll
      for (int reg = 0; reg < 16; ++reg) {
        int m = bx * 256 + CROW(mi, reg);
        pp[(size_t)m * DIN + d] = acc[mi][ni][reg];
      }
  }
}

// K4b: out[(t*B+b), d] = sum_ks part[ks][(b*T+t)][d] + bo[d]
__global__ __launch_bounds__(256) void k_red(const float* __restrict__ part,
                                             const float* __restrict__ bo,
                                             float* __restrict__ out)
{
  int i = blockIdx.x * 256 + threadIdx.x;   // over 8192*64 float4s
  int m = i >> 6, d4 = i & 63;
  float4 s = ((const float4*)part)[i];
#pragma unroll
  for (int ks = 1; ks < 4; ++ks) {
    float4 p = ((const float4*)(part + (size_t)ks * T_SEQ * BATCH * DIN))[i];
    s.x += p.x; s.y += p.y; s.z += p.z; s.w += p.w;
  }
  float4 b4 = ((const float4*)bo)[d4];
  s.x += b4.x; s.y += b4.y; s.z += b4.z; s.w += b4.w;
  int t = m & 1023, b = m >> 10;
  ((float4*)out)[(t * 8 + b) * 64 + d4] = s;
}

// ---------------------------------------------------------------------------
extern "C" void kernel_launch(void* const* d_in, const int* in_sizes, int n_in,
                              void* d_out, int out_size, void* d_ws, size_t ws_size,
                              hipStream_t stream)
{
  const float* Q  = (const float*)d_in[0];
  const float* Wq = (const float*)d_in[1];
  const float* bq = (const float*)d_in[2];
  const float* Wk = (const float*)d_in[3];
  const float* bk = (const float*)d_in[4];
  const float* Wv = (const float*)d_in[5];
  const float* bv = (const float*)d_in[6];
  const float* Wo = (const float*)d_in[7];
  const float* bo = (const float*)d_in[8];
  float* out = (float*)d_out;

  // ---- sizes ----
  const size_t QB_B   = (size_t)T_SEQ * BATCH * DIN * 2;       //  4 MiB
  const size_t W_B    = (size_t)NH * EH * DIN * 2;             //  2 MiB each
  const size_t WO_B   = (size_t)DIN * HE * 2;                  //  2 MiB
  const size_t HMAT_B = (size_t)T_SEQ * BATCH * HE * 2;        // 64 MiB
  const size_t PART_B = (size_t)4 * T_SEQ * BATCH * DIN * 4;   // 32 MiB
  const size_t QKV1   = (size_t)BATCH * T_SEQ * EH * 2;        //  8 MiB / head
  const size_t P1     = (size_t)BATCH * T_SEQ * T_SEQ * 2;     // 16 MiB / head
  const size_t CP1    = (size_t)BATCH * 4 * T_SEQ * 4;         // 128 KiB / head
  const size_t inputsB = QB_B + 3 * W_B + WO_B;                // 12 MiB contiguous

  // ---- largest HG whose plan fits (alias: part <-> P) ----
  int HG = 8;
  for (; HG > 1; HG >>= 1) {
    size_t share = ((size_t)HG * P1 > PART_B) ? (size_t)HG * P1 : PART_B;
    size_t tot = inputsB + 3 * (size_t)HG * QKV1 + share + HMAT_B
               + (size_t)HG * CP1 + 8192;
    if (tot <= ws_size) break;
  }
  size_t shareB = ((size_t)HG * P1 > PART_B) ? (size_t)HG * P1 : PART_B;

  char* w = (char*)d_ws;
  auto alloc = [&](size_t bytes) {
    char* p = w;
    w += (bytes + 255) & ~(size_t)255;
    return p;
  };
  short* Qb   = (short*)alloc(QB_B);
  short* Wqb  = (short*)alloc(W_B);
  short* Wkb  = (short*)alloc(W_B);
  short* Wvb  = (short*)alloc(W_B);
  short* Wob  = (short*)alloc(WO_B);
  float* cpart= (float*)alloc((size_t)HG * CP1);
  short* qb   = (short*)alloc((size_t)HG * QKV1);
  short* kb   = (short*)alloc((size_t)HG * QKV1);
  short* vT   = (short*)alloc((size_t)HG * QKV1);
  char*  shr  = alloc(shareB);                      // P during loop; part after
  short* Hmat = (short*)alloc(HMAT_B);

  short* Pbuf = (short*)shr;
  float* part = (float*)shr;

  k_cvt_all<<<dim3(2048), 256, 0, stream>>>(Q, Wq, Wk, Wv, Wo, Qb);

  for (int h0 = 0; h0 < NH; h0 += HG) {
    k_projqk<<<dim3(128, 2 * HG), 512, 0, stream>>>(Qb, Wqb, Wkb, bq, bk,
                                                    qb, kb, h0, HG);
    k_projv <<<dim3(128, HG), 512, 0, stream>>>(Qb, Wvb, bv, vT, h0, HG);
    k_pgen  <<<dim3(4, 8, HG * 8), 512, 0, stream>>>(qb, kb, Pbuf, cpart, HG);
    k_scalev<<<dim3(8, HG * 8), 256, 0, stream>>>(vT, cpart, HG);
    k_ogemm <<<dim3(4, 4, HG * 8), 512, 0, stream>>>(Pbuf, vT, Hmat, h0, HG);
  }
  k_final<<<dim3(32, 2, 4), 512, 0, stream>>>(Hmat, Wob, part);
  k_red  <<<dim3(T_SEQ * BATCH * DIN / 4 / 256), 256, 0, stream>>>(part, bo, out);
}

// Round 8
// 365.530 us; speedup vs baseline: 1.1854x; 1.0180x over previous
//
#include <hip/hip_runtime.h>
#include <stdint.h>
#include <stddef.h>

// Problem constants (MultiHeadAttention_52759378264454)
constexpr int T_SEQ = 1024;
constexpr int BATCH = 8;
constexpr int DIN   = 256;
constexpr int NH    = 8;
constexpr int EH    = 512;
constexpr int HE    = NH * EH;   // 4096
constexpr float SCALE = 0.044194173824159216f; // 1/sqrt(512)

typedef __attribute__((ext_vector_type(8)))  short s16x8;
typedef __attribute__((ext_vector_type(4)))  short s16x4;
typedef __attribute__((ext_vector_type(16))) float f32x16;

__device__ __forceinline__ short f2bf(float f) {
  union { float f; uint32_t u; } c; c.f = f;
  uint32_t u = c.u;
  u += 0x7fffu + ((u >> 16) & 1u);   // RNE
  return (short)(u >> 16);
}
__device__ __forceinline__ float bf2f(short s) {
  union { uint32_t u; float f; } c; c.u = ((uint32_t)(uint16_t)s) << 16;
  return c.f;
}

// async global->LDS, 16B/lane. LDS dest = wave-uniform base + lane*16 (HW).
__device__ __forceinline__ void gload16(const short* g, short* l) {
  __builtin_amdgcn_global_load_lds(
      (__attribute__((address_space(1))) void*)(void*)const_cast<short*>(g),
      (__attribute__((address_space(3))) void*)(void*)l, 16, 0, 0);
}

#define WAITVM(N) asm volatile("s_waitcnt vmcnt(" #N ")" ::: "memory")
#define BARF do { asm volatile("" ::: "memory"); __builtin_amdgcn_s_barrier(); \
                  asm volatile("" ::: "memory"); } while (0)

// ---------------------------------------------------------------------------
// 8-wave 256x128 GEMM, BK=32, mfma_f32_32x32x16_bf16.
// v2 schedule: 3-slot circular LDS (72 KB), ONE barrier + ONE counted
// vmcnt per K-tile, stage(t+2) issued right after the barrier so its HBM
// latency hides under this tile's ds_read+MFMA (T3/T4: loads span barriers,
// vmcnt(3) steady state, 6 loads in flight).
// WAR safety: slot (t+2)%3 was last read at iter t-1; the iter-t barrier
// is only passed once every wave consumed its reads (lgkmcnt before MFMA).
// C[256,128] += A[256,K]*B[128,K]^T, K-major bf16. Waves 4wm x 2wn, 64x64 ea.
// NOTE: no trailing barrier after the loop — callers must __syncthreads()
// before reusing LDS.
// ---------------------------------------------------------------------------
template<int NT>   // K = NT*32, NT >= 2
__device__ __forceinline__ void gemm32(const short* __restrict__ Ag, int lda,
                                       const short* __restrict__ Bg, int ldb,
                                       short* lds, f32x16 (&acc)[2][2])
{
  const int tid = threadIdx.x;
  const int l   = tid & 63, wv = tid >> 6;
  const int hi  = l >> 5;
  const int Rw  = (wv >> 1) * 64, Cw = (wv & 1) * 64;
  const int fl  = (l & 3) ^ ((l >> 2) & 3);

  int oA[2][2], oB[2][2];
#pragma unroll
  for (int kk = 0; kk < 2; ++kk) {
    int cp = (((kk << 1) | hi) ^ fl) * 8;
#pragma unroll
    for (int mi = 0; mi < 2; ++mi) oA[kk][mi] = (Rw + mi * 32 + (l & 31)) * 32 + cp;
#pragma unroll
    for (int ni = 0; ni < 2; ++ni) oB[kk][ni] = 8192 + (Cw + ni * 32 + (l & 31)) * 32 + cp;
  }

  const int rA0 = tid >> 2;
  const int sA0 = ((tid & 3) ^ ((rA0 & 3) ^ ((rA0 >> 2) & 3))) * 8;
  const int cA1 = tid + 512, rA1 = cA1 >> 2;
  const int sA1 = ((cA1 & 3) ^ ((rA1 & 3) ^ ((rA1 >> 2) & 3))) * 8;
  const int dA0 = (wv * 64) * 8, dA1 = (wv * 64 + 512) * 8, dB0 = 8192 + (wv * 64) * 8;

  auto stage = [&](int t, short* slot) {
    const int ko = t * 32;
    gload16(Ag + (size_t)rA0 * lda + ko + sA0, slot + dA0);
    gload16(Ag + (size_t)rA1 * lda + ko + sA1, slot + dA1);
    gload16(Bg + (size_t)rA0 * ldb + ko + sA0, slot + dB0);
  };

  stage(0, lds); stage(1, lds + 12288);   // 6 loads in flight

  int sl = 0, sl2 = 24576;    // slot offsets (shorts): tile t, tile t+2
#pragma unroll 1
  for (int t = 0; t < NT; ++t) {
    const short* buf = lds + sl;
    if (t == NT - 1) { WAITVM(0); } else { WAITVM(3); }
    BARF;
    if (t + 2 < NT) stage(t + 2, lds + sl2);   // overlaps with compute below
#pragma unroll
    for (int kk = 0; kk < 2; ++kk) {
      s16x8 a0 = *(const s16x8*)(buf + oA[kk][0]);
      s16x8 a1 = *(const s16x8*)(buf + oA[kk][1]);
      s16x8 b0 = *(const s16x8*)(buf + oB[kk][0]);
      s16x8 b1 = *(const s16x8*)(buf + oB[kk][1]);
      __builtin_amdgcn_s_setprio(1);
      acc[0][0] = __builtin_amdgcn_mfma_f32_32x32x16_bf16(a0, b0, acc[0][0], 0, 0, 0);
      acc[0][1] = __builtin_amdgcn_mfma_f32_32x32x16_bf16(a0, b1, acc[0][1], 0, 0, 0);
      acc[1][0] = __builtin_amdgcn_mfma_f32_32x32x16_bf16(a1, b0, acc[1][0], 0, 0, 0);
      acc[1][1] = __builtin_amdgcn_mfma_f32_32x32x16_bf16(a1, b1, acc[1][1], 0, 0, 0);
      __builtin_amdgcn_s_setprio(0);
    }
    sl  = (sl  == 24576) ? 0 : sl  + 12288;
    sl2 = (sl2 == 24576) ? 0 : sl2 + 12288;
  }
}

#define CROW(mi, reg) ((wv >> 1) * 64 + (mi) * 32 + ((reg) & 3) + 8 * ((reg) >> 2) + 4 * hi)
#define CCOL(ni)      ((wv & 1) * 64 + (ni) * 32 + (l & 31))

// ---------------------------------------------------------------------------
// K0: fused fp32->bf16 cast; Qb transposed to [b][t][d]; weights copied.
// ---------------------------------------------------------------------------
__global__ __launch_bounds__(256) void k_cvt_all(
    const float* __restrict__ Q,  const float* __restrict__ Wq,
    const float* __restrict__ Wk, const float* __restrict__ Wv,
    const float* __restrict__ Wo, short* __restrict__ dst)
{
  constexpr int N_Q = 524288;              // 1024*8*256/4
  constexpr int N_W = 262144;              // 8*512*256/4
  constexpr int TOT = N_Q + 4 * N_W;
  int i  = blockIdx.x * 256 + threadIdx.x;
  int st = gridDim.x * 256;
  for (; i < TOT; i += st) {
    const float* s; int off;
    if (i < N_Q) {
      int b = i >> 16, t = (i >> 6) & 1023, d4 = i & 63;
      s = Q; off = (t * 8 + b) * 64 + d4;
    }
    else if (i < N_Q + N_W)     { s = Wq; off = i - N_Q; }
    else if (i < N_Q + 2 * N_W) { s = Wk; off = i - N_Q - N_W; }
    else if (i < N_Q + 3 * N_W) { s = Wv; off = i - N_Q - 2 * N_W; }
    else                        { s = Wo; off = i - N_Q - 3 * N_W; }
    float4 v = ((const float4*)s)[off];
    s16x4 o = { f2bf(v.x), f2bf(v.y), f2bf(v.z), f2bf(v.w) };
    ((s16x4*)dst)[i] = o;
  }
}

// ---------------------------------------------------------------------------
// K1a: Q/K projection. C[m,e] = sum_d Qb[m,d]*W[h,e,d] + bias.
// grid (128, 2*HG). Sharer-aware XCD map: bx&7 == XCD (A-tile reuse in L2).
// ---------------------------------------------------------------------------
__global__ __launch_bounds__(512, 4) void k_projqk(
    const short* __restrict__ Qb,
    const short* __restrict__ Wqb, const short* __restrict__ Wkb,
    const float* __restrict__ bq, const float* __restrict__ bk,
    short* __restrict__ qb, short* __restrict__ kb, int h0, int HG)
{
  __shared__ short lds[36864];
  int f = blockIdx.x + (blockIdx.y << 7);
  int bx = (f & 7) + 8 * ((f >> 3) & 3);
  int rest = f >> 5;
  int by = rest & 3, z = rest >> 2;           // z in [0, 2HG)
  int p = z / HG, hh = z % HG, h = h0 + hh;

  const short* W    = (p == 0 ? Wqb : Wkb) + ((size_t)h * EH + (size_t)by * 128) * DIN;
  const float* bias = (p == 0 ? bq  : bk ) + h * EH + by * 128;
  short* outp       = (p == 0 ? qb  : kb ) + (size_t)hh * BATCH * T_SEQ * EH;
  const short* Ag   = Qb + (size_t)bx * 256 * DIN;

  f32x16 acc[2][2] = {};
  gemm32<DIN / 32>(Ag, DIN, W, DIN, lds, acc);

  const int l = threadIdx.x & 63, wv = threadIdx.x >> 6, hi = l >> 5;
#pragma unroll
  for (int ni = 0; ni < 2; ++ni) {
    int coll = CCOL(ni);
    float bia = bias[coll];
    int e = by * 128 + coll;
#pragma unroll
    for (int mi = 0; mi < 2; ++mi)
#pragma unroll
      for (int reg = 0; reg < 16; ++reg) {
        int m = bx * 256 + CROW(mi, reg);
        outp[(size_t)m * EH + e] = f2bf(acc[mi][ni][reg] + bia);
      }
  }
}

// ---------------------------------------------------------------------------
// K1b: V projection TRANSPOSED: C[e, m] = sum_d Wv[h,e,d]*Qb[m,d] + bv[h,e]
// -> vT[hh][e][m], m = b*1024 + t.  grid (128, HG)
// ---------------------------------------------------------------------------
__global__ __launch_bounds__(512, 4) void k_projv(
    const short* __restrict__ Qb, const short* __restrict__ Wvb,
    const float* __restrict__ bv, short* __restrict__ vT, int h0, int HG)
{
  __shared__ short lds[36864];
  int f = blockIdx.x + (blockIdx.y << 7);
  int bn = (f & 7) + 8 * ((f >> 3) & 7);      // [0,64) m-tile
  int rest = f >> 6;
  int bm = rest & 1, hh = rest >> 1, h = h0 + hh;

  const short* Ag = Wvb + ((size_t)h * EH + (size_t)bm * 256) * DIN;
  const short* Bg = Qb + (size_t)bn * 128 * DIN;

  f32x16 acc[2][2] = {};
  gemm32<DIN / 32>(Ag, DIN, Bg, DIN, lds, acc);

  short* outp = vT + (size_t)hh * EH * (BATCH * T_SEQ);
  const int l = threadIdx.x & 63, wv = threadIdx.x >> 6, hi = l >> 5;
#pragma unroll
  for (int ni = 0; ni < 2; ++ni) {
    int m = bn * 128 + CCOL(ni);
#pragma unroll
    for (int mi = 0; mi < 2; ++mi)
#pragma unroll
      for (int reg = 0; reg < 16; ++reg) {
        int e = bm * 256 + CROW(mi, reg);
        float bia = bv[h * EH + e];
        outp[(size_t)e * (BATCH * T_SEQ) + m] = f2bf(acc[mi][ni][reg] + bia);
      }
  }
}

// ---------------------------------------------------------------------------
// K3a: P[t,s] = exp(SCALE*q.k) bf16 (unnormalized) + per-block column sums.
// grid (4, 8, HG*8); same-z blocks grouped per XCD (q/k L2 reuse).
// ---------------------------------------------------------------------------
__global__ __launch_bounds__(512, 4) void k_pgen(
    const short* __restrict__ qb, const short* __restrict__ kb,
    short* __restrict__ Pbuf, float* __restrict__ colpart, int HG)
{
  __shared__ short lds[36864];
  int f = blockIdx.x + (blockIdx.y << 2) + (blockIdx.z << 5);
  int xcd = f & 7, rest = f >> 3;
  int zi = rest % HG, rb = rest / HG;
  int z = xcd * HG + zi;
  int bx = rb & 3, by = rb >> 2;

  const short* Ag = qb + (size_t)z * T_SEQ * EH + (size_t)bx * 256 * EH;
  const short* Bg = kb + (size_t)z * T_SEQ * EH + (size_t)by * 128 * EH;

  f32x16 acc[2][2] = {};
  gemm32<EH / 32>(Ag, EH, Bg, EH, lds, acc);

  short* Pb = Pbuf + (size_t)z * T_SEQ * T_SEQ;
  const int l = threadIdx.x & 63, wv = threadIdx.x >> 6, hi = l >> 5;

  float cs[2] = {0.f, 0.f};
#pragma unroll
  for (int ni = 0; ni < 2; ++ni) {
    int s = by * 128 + CCOL(ni);
#pragma unroll
    for (int mi = 0; mi < 2; ++mi)
#pragma unroll
      for (int reg = 0; reg < 16; ++reg) {
        int tq = bx * 256 + CROW(mi, reg);
        float ev = __expf(acc[mi][ni][reg] * SCALE);
        cs[ni] += ev;
        Pb[(size_t)tq * T_SEQ + s] = f2bf(ev);
      }
  }
  cs[0] += __shfl_xor(cs[0], 32);
  cs[1] += __shfl_xor(cs[1], 32);
  __syncthreads();              // loop has no trailing barrier; LDS reused below
  float* csL = (float*)lds;
  if (l < 32) {
#pragma unroll
    for (int ni = 0; ni < 2; ++ni) csL[(wv >> 1) * 128 + CCOL(ni)] = cs[ni];
  }
  __syncthreads();
  if (threadIdx.x < 128) {
    float tot = csL[threadIdx.x] + csL[128 + threadIdx.x] +
                csL[256 + threadIdx.x] + csL[384 + threadIdx.x];
    colpart[((size_t)z * 4 + bx) * T_SEQ + by * 128 + threadIdx.x] = tot;
  }
}

// ---------------------------------------------------------------------------
// K2: scale V in place by the softmax normalizer (fused invsum):
// vT[hh][e][m] *= 1 / sum_p colpart[(z*4+p)][t],  z = hh*8+b, m = b*1024+t
// grid (8 e-tiles, HG*8 z), 256 thr. Each block: 64 e-rows x 1024 t.
// ---------------------------------------------------------------------------
__global__ __launch_bounds__(256) void k_scalev(
    short* __restrict__ vT, const float* __restrict__ colpart, int HG)
{
  __shared__ float invL[1024];
  const int et = blockIdx.x, z = blockIdx.y;
  const int hh = z >> 3, b = z & 7;
  const int tid = threadIdx.x;

#pragma unroll
  for (int it = 0; it < 4; ++it) {
    int t = it * 256 + tid;
    float s = 0.f;
#pragma unroll
    for (int p = 0; p < 4; ++p) s += colpart[((size_t)z * 4 + p) * T_SEQ + t];
    invL[t] = 1.0f / s;
  }
  __syncthreads();

  short* base = vT + (size_t)hh * EH * (BATCH * T_SEQ)
                   + (size_t)et * 64 * (BATCH * T_SEQ) + (size_t)b * T_SEQ;
  for (int c = tid; c < 64 * 128; c += 256) {
    int row = c >> 7, col = (c & 127) * 8;
    short* p = &base[(size_t)row * (BATCH * T_SEQ) + col];
    s16x8 v = *(s16x8*)p;
#pragma unroll
    for (int j = 0; j < 8; ++j) v[j] = f2bf(bf2f(v[j]) * invL[col + j]);
    *(s16x8*)p = v;
  }
}

// ---------------------------------------------------------------------------
// K3b: O[t,e] = sum_s P[t,s]*vT[e,s] -> Hmat[(b*T+t), h*EH+e]
// grid (4, 4, HG*8); same-z grouped per XCD.
// ---------------------------------------------------------------------------
__global__ __launch_bounds__(512, 4) void k_ogemm(
    const short* __restrict__ Pbuf, const short* __restrict__ vT,
    short* __restrict__ Hmat, int h0, int HG)
{
  __shared__ short lds[36864];
  int f = blockIdx.x + (blockIdx.y << 2) + (blockIdx.z << 4);
  int xcd = f & 7, rest = f >> 3;
  int zi = rest % HG, rb = rest / HG;
  int z = xcd * HG + zi;
  int bx = rb & 3, by = rb >> 2;
  const int hh = z >> 3, b = z & 7, h = h0 + hh;

  const short* Ag = Pbuf + (size_t)z * T_SEQ * T_SEQ + (size_t)bx * 256 * T_SEQ;
  const short* Bg = vT + ((size_t)hh * EH + (size_t)by * 128) * (BATCH * T_SEQ)
                       + (size_t)b * T_SEQ;

  f32x16 acc[2][2] = {};
  gemm32<T_SEQ / 32>(Ag, T_SEQ, Bg, BATCH * T_SEQ, lds, acc);

  const int l = threadIdx.x & 63, wv = threadIdx.x >> 6, hi = l >> 5;
#pragma unroll
  for (int ni = 0; ni < 2; ++ni) {
    int e = by * 128 + CCOL(ni);
#pragma unroll
    for (int mi = 0; mi < 2; ++mi)
#pragma unroll
      for (int reg = 0; reg < 16; ++reg) {
        int tq = bx * 256 + CROW(mi, reg);
        Hmat[((size_t)b * T_SEQ + tq) * HE + (size_t)h * EH + e] = f2bf(acc[mi][ni][reg]);
      }
  }
}

// ---------------------------------------------------------------------------
// K4a: split-K(4) output GEMM. part[ks][m][d] over K=1024 slice. grid (32,2,4)
// ---------------------------------------------------------------------------
__global__ __launch_bounds__(512, 4) void k_final(
    const short* __restrict__ Hmat, const short* __restrict__ Wob,
    float* __restrict__ part)
{
  __shared__ short lds[36864];
  int orig = blockIdx.x + (blockIdx.y << 5) + (blockIdx.z << 6);
  int swz  = (orig & 7) * 32 + (orig >> 3);     // nwg = 256
  const int bx = swz & 31, by = (swz >> 5) & 1, ks = swz >> 6;

  const short* Ag = Hmat + (size_t)bx * 256 * HE + (size_t)ks * 1024;
  const short* Bg = Wob  + (size_t)by * 128 * HE + (size_t)ks * 1024;

  f32x16 acc[2][2] = {};
  gemm32<1024 / 32>(Ag, HE, Bg, HE, lds, acc);

  float* pp = part + (size_t)ks * (T_SEQ * BATCH) * DIN;
  const int l = threadIdx.x & 63, wv = threadIdx.x >> 6, hi = l >> 5;
#pragma unroll
  for (int ni = 0; ni < 2; ++ni) {
    int d = by * 128 + CCOL(ni);
#pragma unroll
    for (int mi = 0; mi < 2; ++mi)
#pragma unroll
      for (int reg = 0; reg < 16; ++reg) {
        int m = bx * 256 + CROW(mi, reg);
        pp[(size_t)m * DIN + d] = acc[mi][ni][reg];
      }
  }
}

// K4b: out[(t*B+b), d] = sum_ks part[ks][(b*T+t)][d] + bo[d]
__global__ __launch_bounds__(256) void k_red(const float* __restrict__ part,
                                             const float* __restrict__ bo,
                                             float* __restrict__ out)
{
  int i = blockIdx.x * 256 + threadIdx.x;   // over 8192*64 float4s
  int m = i >> 6, d4 = i & 63;
  float4 s = ((const float4*)part)[i];
#pragma unroll
  for (int ks = 1; ks < 4; ++ks) {
    float4 p = ((const float4*)(part + (size_t)ks * T_SEQ * BATCH * DIN))[i];
    s.x += p.x; s.y += p.y; s.z += p.z; s.w += p.w;
  }
  float4 b4 = ((const float4*)bo)[d4];
  s.x += b4.x; s.y += b4.y; s.z += b4.z; s.w += b4.w;
  int t = m & 1023, b = m >> 10;
  ((float4*)out)[(t * 8 + b) * 64 + d4] = s;
}

// ---------------------------------------------------------------------------
extern "C" void kernel_launch(void* const* d_in, const int* in_sizes, int n_in,
                              void* d_out, int out_size, void* d_ws, size_t ws_size,
                              hipStream_t stream)
{
  const float* Q  = (const float*)d_in[0];
  const float* Wq = (const float*)d_in[1];
  const float* bq = (const float*)d_in[2];
  const float* Wk = (const float*)d_in[3];
  const float* bk = (const float*)d_in[4];
  const float* Wv = (const float*)d_in[5];
  const float* bv = (const float*)d_in[6];
  const float* Wo = (const float*)d_in[7];
  const float* bo = (const float*)d_in[8];
  float* out = (float*)d_out;

  // ---- sizes ----
  const size_t QB_B   = (size_t)T_SEQ * BATCH * DIN * 2;       //  4 MiB
  const size_t W_B    = (size_t)NH * EH * DIN * 2;             //  2 MiB each
  const size_t WO_B   = (size_t)DIN * HE * 2;                  //  2 MiB
  const size_t HMAT_B = (size_t)T_SEQ * BATCH * HE * 2;        // 64 MiB
  const size_t PART_B = (size_t)4 * T_SEQ * BATCH * DIN * 4;   // 32 MiB
  const size_t QKV1   = (size_t)BATCH * T_SEQ * EH * 2;        //  8 MiB / head
  const size_t P1     = (size_t)BATCH * T_SEQ * T_SEQ * 2;     // 16 MiB / head
  const size_t CP1    = (size_t)BATCH * 4 * T_SEQ * 4;         // 128 KiB / head
  const size_t inputsB = QB_B + 3 * W_B + WO_B;                // 12 MiB contiguous

  // ---- largest HG whose plan fits (alias: part <-> P) ----
  int HG = 8;
  for (; HG > 1; HG >>= 1) {
    size_t share = ((size_t)HG * P1 > PART_B) ? (size_t)HG * P1 : PART_B;
    size_t tot = inputsB + 3 * (size_t)HG * QKV1 + share + HMAT_B
               + (size_t)HG * CP1 + 8192;
    if (tot <= ws_size) break;
  }
  size_t shareB = ((size_t)HG * P1 > PART_B) ? (size_t)HG * P1 : PART_B;

  char* w = (char*)d_ws;
  auto alloc = [&](size_t bytes) {
    char* p = w;
    w += (bytes + 255) & ~(size_t)255;
    return p;
  };
  short* Qb   = (short*)alloc(QB_B);
  short* Wqb  = (short*)alloc(W_B);
  short* Wkb  = (short*)alloc(W_B);
  short* Wvb  = (short*)alloc(W_B);
  short* Wob  = (short*)alloc(WO_B);
  float* cpart= (float*)alloc((size_t)HG * CP1);
  short* qb   = (short*)alloc((size_t)HG * QKV1);
  short* kb   = (short*)alloc((size_t)HG * QKV1);
  short* vT   = (short*)alloc((size_t)HG * QKV1);
  char*  shr  = alloc(shareB);                      // P during loop; part after
  short* Hmat = (short*)alloc(HMAT_B);

  short* Pbuf = (short*)shr;
  float* part = (float*)shr;

  k_cvt_all<<<dim3(2048), 256, 0, stream>>>(Q, Wq, Wk, Wv, Wo, Qb);

  for (int h0 = 0; h0 < NH; h0 += HG) {
    k_projqk<<<dim3(128, 2 * HG), 512, 0, stream>>>(Qb, Wqb, Wkb, bq, bk,
                                                    qb, kb, h0, HG);
    k_projv <<<dim3(128, HG), 512, 0, stream>>>(Qb, Wvb, bv, vT, h0, HG);
    k_pgen  <<<dim3(4, 8, HG * 8), 512, 0, stream>>>(qb, kb, Pbuf, cpart, HG);
    k_scalev<<<dim3(8, HG * 8), 256, 0, stream>>>(vT, cpart, HG);
    k_ogemm <<<dim3(4, 4, HG * 8), 512, 0, stream>>>(Pbuf, vT, Hmat, h0, HG);
  }
  k_final<<<dim3(32, 2, 4), 512, 0, stream>>>(Hmat, Wob, part);
  k_red  <<<dim3(T_SEQ * BATCH * DIN / 4 / 256), 256, 0, stream>>>(part, bo, out);
}